// Round 9
// baseline (202.145 us; speedup 1.0000x reference)
//
#include <hip/hip_runtime.h>

#define NB 16384
#define ND 512
#define NH 128
#define NHH 256
#define NG 18

typedef short s8v __attribute__((ext_vector_type(8)));
typedef __bf16 bf8v __attribute__((ext_vector_type(8)));
typedef float f16v __attribute__((ext_vector_type(16)));
typedef unsigned int u4v __attribute__((ext_vector_type(4)));

static __device__ __forceinline__ unsigned short f2bf(float f) {
  unsigned int u = __builtin_bit_cast(unsigned int, f);
  u += 0x7FFFu + ((u >> 16) & 1u);
  return (unsigned short)(u >> 16);
}

static __device__ __forceinline__ f16v mfma32(s8v a, s8v b, f16v c) {
  return __builtin_amdgcn_mfma_f32_32x32x16_bf16(
      __builtin_bit_cast(bf8v, a), __builtin_bit_cast(bf8v, b), c, 0, 0, 0);
}

static __device__ __forceinline__ f16v zf16() {
  f16v v;
#pragma unroll
  for (int i = 0; i < 16; ++i) v[i] = 0.f;
  return v;
}

// per-ks compile-time swizzle XOR for fragment-linear H1/H2 reads
#define KM(ks) (((((ks) & 1) << 5)) | ((((ks) >> 1) & 1) << 6))

// pack W [G][K][N] f32 -> B-fragment-linear bf16 for mfma_32x32x16:
// out[g][((nt*(K/16)+ks)*64 + l)*8 + j] = W[g][ks*16+(l>>5)*8+j][nt*32+(l&31)]
__global__ __launch_bounds__(256) void k_pack(const float* __restrict__ in,
                                              unsigned short* __restrict__ out,
                                              int K, int N) {
  const int g = blockIdx.y;
  const int c = blockIdx.x * 256 + threadIdx.x;
  const int nk = K >> 4;
  const int l = c & 63;
  const int t = c >> 6;
  const int nt = t / nk;
  const int ks = t - nt * nk;
  const int k0 = (ks << 4) + ((l >> 5) << 3);
  const int col = (nt << 5) + (l & 31);
  const float* ip = in + (size_t)g * K * N + (size_t)k0 * N + col;
  u4v pk;
#pragma unroll
  for (int j = 0; j < 4; ++j) {
    float x0 = ip[(size_t)(2 * j) * N];
    float x1 = ip[(size_t)(2 * j + 1) * N];
    pk[j] = (unsigned)f2bf(x0) | ((unsigned)f2bf(x1) << 16);
  }
  *(u4v*)(out + (size_t)g * K * N + ((size_t)c << 3)) = pk;
}

// Wa [512][18] -> WaT [18][512] f32
__global__ __launch_bounds__(256) void k_wat(const float* __restrict__ wa,
                                             float* __restrict__ wat) {
  int tid = blockIdx.x * 256 + threadIdx.x;
  if (tid < NG * ND) {
    int g = tid >> 9, d = tid & (ND - 1);
    wat[tid] = wa[d * NG + g];
  }
}

// attention weights w[B,G] = softmax(X@Wa+ba)*gv, plus X -> bf16
__global__ __launch_bounds__(256) void k_attn(const float* __restrict__ X,
                                              const float* __restrict__ GV,
                                              const float* __restrict__ wat,
                                              const float* __restrict__ ba,
                                              float* __restrict__ w,
                                              unsigned short* __restrict__ xb) {
  __shared__ float wl[NG * ND];
  const int tid = threadIdx.x;
  for (int i = tid; i < NG * ND; i += 256) wl[i] = wat[i];
  __syncthreads();
  const int lane = tid & 63;
  const int row = (blockIdx.x << 2) + (tid >> 6);
  const float* xr = X + (size_t)row * ND + (lane << 3);
  float x[8];
  {
    float4 a = *(const float4*)xr;
    float4 b = *(const float4*)(xr + 4);
    x[0] = a.x; x[1] = a.y; x[2] = a.z; x[3] = a.w;
    x[4] = b.x; x[5] = b.y; x[6] = b.z; x[7] = b.w;
  }
  {
    u4v p;
#pragma unroll
    for (int j = 0; j < 4; ++j)
      p[j] = (unsigned)f2bf(x[2 * j]) | ((unsigned)f2bf(x[2 * j + 1]) << 16);
    *(u4v*)(xb + (size_t)row * ND + (lane << 3)) = p;
  }
  float lg[NG];
#pragma unroll
  for (int g = 0; g < NG; ++g) {
    const float* wr = wl + g * ND + (lane << 3);
    float s = 0.f;
#pragma unroll
    for (int j = 0; j < 8; ++j) s += x[j] * wr[j];
    lg[g] = s;
  }
#pragma unroll
  for (int off = 32; off > 0; off >>= 1) {
#pragma unroll
    for (int g = 0; g < NG; ++g) lg[g] += __shfl_xor(lg[g], off);
  }
  float m = -3.4e38f;
#pragma unroll
  for (int g = 0; g < NG; ++g) { lg[g] += ba[g]; m = fmaxf(m, lg[g]); }
  float s = 0.f;
#pragma unroll
  for (int g = 0; g < NG; ++g) { lg[g] = expf(lg[g] - m); s += lg[g]; }
  float inv = 1.f / s;
  if (lane < NG) {
    float gv = GV[(size_t)row * NG + lane];
    w[(size_t)row * NG + lane] = gv > 0.f ? lg[lane] * inv * gv : 0.f;
  }
}

// fused experts + aggregation. 1 block = 64 rows, 8 waves, mfma 32x32x16.
// GEMM1: 1 row-tile x 2 col-tiles per wave (halves LDS A-reads).
// H1/H2 XOR-swizzled (bit9..11 -> bit4..6) so epilogue 2B writes are conflict-free.
__global__ __launch_bounds__(512, 2) void k_main(
    const unsigned short* __restrict__ xb,    // [B][512] bf16 (row-linear)
    const float* __restrict__ wbg,            // [B][18]
    const unsigned short* __restrict__ w1p,   // packed [18][512x256]
    const unsigned short* __restrict__ w2p,   // packed [18][256x128]
    const unsigned short* __restrict__ w3p,   // packed [18][128x128]
    const unsigned short* __restrict__ w4p,   // packed [640x512]
    const float* __restrict__ b1, const float* __restrict__ b2,
    const float* __restrict__ b3, const float* __restrict__ bagg,
    float* __restrict__ out) {
  __shared__ __align__(16) char smem[119808];
  char* const XT = smem;                      // [2][32][1024] = 64KB (no swz)
  char* const H1 = smem + 65536;              // [2][16][1024] = 32KB (swz)
  char* const H2 = smem + 98304;              // [2][8][1024]  = 16KB (swz)
  float* const WL = (float*)(smem + 114688);  // [64][20]

  const int tid = threadIdx.x;
  const int row0 = blockIdx.x << 6;
  const int wid = tid >> 6, lane = tid & 63;
  const int l31 = lane & 31, lh = lane >> 5;
  const int lb = (lane << 4) ^ (lh << 4);     // swizzled read lane-base

  // ---- stage XT in fragment-linear order (scatter-read global, linear LDS write)
#pragma unroll
  for (int i = 0; i < 8; ++i) {
    int ck = (i << 9) + tid;                 // chunk 0..4095
    int mt = ck >> 11, ks = (ck >> 6) & 31, l = ck & 63;
    int grow = row0 + (mt << 5) + (l & 31);
    int col8 = (ks << 1) + (l >> 5);
    *(u4v*)(XT + (ck << 4)) =
        *(const u4v*)(xb + ((size_t)grow << 9) + (col8 << 3));
  }
  for (int i = tid; i < 64 * NG; i += 512) {
    int r = i / NG, g = i - r * NG;
    WL[r * 20 + g] = wbg[(size_t)(row0 + r) * NG + g];
  }

  // ---- wave tile assignment
  const int mt1 = wid >> 2;                  // GEMM1 row-tile
  const int ntp = (wid & 3) << 1;            // GEMM1 col-tile pair base
  const int nt2 = wid & 3, mt2 = wid >> 2;   // GEMM2/3 tile

  // packed-B per-wave bases (element offsets)
  const unsigned short* const bp1A = w1p + (ntp << 14) + (lane << 3);
  const unsigned short* const bp1B = w1p + ((ntp + 1) << 14) + (lane << 3);
  const unsigned short* const bp2 = w2p + (nt2 << 13) + (lane << 3);
  const unsigned short* const bp3 = w3p + (nt2 << 12) + (lane << 3);
  const unsigned short* const bp4a = w4p + (size_t)wid * 20480 + (lane << 3);
  const unsigned short* const bp4b = w4p + (size_t)(wid + 8) * 20480 + (lane << 3);

  // per-lane swizzled write bases (genre-invariant)
  const int gcA = (ntp << 5) + l31;          // GEMM1 colA
  const int gcB = gcA + 32;                  // GEMM1 colB
  const int gc2 = (nt2 << 5) + l31;          // GEMM2/3 col
  const int cbA = ((gcA >> 4) << 10) + (((gcA >> 3) & 1) << 9) + ((gcA & 7) << 1);
  const int cbB = ((gcB >> 4) << 10) + (((gcB >> 3) & 1) << 9) + ((gcB & 7) << 1);
  const int cb2 = ((gc2 >> 4) << 10) + (((gc2 >> 3) & 1) << 9) + ((gc2 & 7) << 1);
  const int mA = (((cbA >> 9) & 1) << 4) | (((cbA >> 10) & 1) << 5) | (((cbA >> 11) & 1) << 6);
  const int mB = (((cbB >> 9) & 1) << 4) | (((cbB >> 10) & 1) << 5) | (((cbB >> 11) & 1) << 6);
  const int m2 = (((cb2 >> 9) & 1) << 4) | (((cb2 >> 10) & 1) << 5) | (((cb2 >> 11) & 1) << 6);

  // prefetch GEMM1 g=0 ks=0..3 B for both col-tiles (drains under staging barrier)
  s8v bqA[4], bqB[4];
#pragma unroll
  for (int i = 0; i < 4; ++i) {
    bqA[i] = *(const s8v*)(bp1A + (i << 9));
    bqB[i] = *(const s8v*)(bp1B + (i << 9));
  }

  f16v racc = zf16();
  __syncthreads();

  for (int g = 0; g < NG; ++g) {
    const unsigned short* const bp1Ag = bp1A + (size_t)g * 131072;
    const unsigned short* const bp1Bg = bp1B + (size_t)g * 131072;
    // ---------- GEMM1: h1 = relu(X @ W1[g] + b1[g])  [64,256] ----------
    f16v accA = zf16(), accB = zf16();
#pragma unroll
    for (int ks = 0; ks < 32; ++ks) {
      s8v bnA, bnB;
      const bool havenext = (ks < 28) || (g + 1 < NG);
      if (havenext) {
        size_t off = (ks < 28) ? (size_t)((ks + 4) << 9)
                               : (size_t)131072 + ((ks - 28) << 9);
        bnA = *(const s8v*)(bp1Ag + off);
        bnB = *(const s8v*)(bp1Bg + off);
      }
      s8v a = *(const s8v*)(XT + (mt1 << 15) + (ks << 10) + (lane << 4));
      accA = mfma32(a, bqA[ks & 3], accA);
      accB = mfma32(a, bqB[ks & 3], accB);
      if (havenext) { bqA[ks & 3] = bnA; bqB[ks & 3] = bnB; }
    }
    {
      const float bv1a = b1[(g << 8) + gcA];
      const float bv1b = b1[(g << 8) + gcB];
#pragma unroll
      for (int r = 0; r < 16; ++r) {
        const int rl = (r & 3) + ((r >> 2) << 3) + (lh << 2);
        float vA = fmaxf(accA[r] + bv1a, 0.f);
        float vB = fmaxf(accB[r] + bv1b, 0.f);
        *(unsigned short*)(H1 + (mt1 << 14) + ((cbA + (rl << 4)) ^ mA)) = f2bf(vA);
        *(unsigned short*)(H1 + (mt1 << 14) + ((cbB + (rl << 4)) ^ mB)) = f2bf(vB);
      }
    }
    // hoist ALL GEMM2 B-fragments + bias across the barrier
    const unsigned short* const bp2g = bp2 + ((size_t)g << 15);
    s8v b2f[16];
#pragma unroll
    for (int ks = 0; ks < 16; ++ks) b2f[ks] = *(const s8v*)(bp2g + (ks << 9));
    const float bv2 = b2[(g << 7) + gc2];
    __syncthreads();

    // ---------- GEMM2: h2 = relu(h1 @ W2[g] + b2[g])  [64,128] ----------
    f16v acc2a = zf16(), acc2b = zf16();
#pragma unroll
    for (int ks = 0; ks < 16; ks += 2) {
      s8v a0 = *(const s8v*)(H1 + (mt2 << 14) + (((ks << 10) + lb) ^ KM(ks)));
      s8v a1 = *(const s8v*)(H1 + (mt2 << 14) + ((((ks + 1) << 10) + lb) ^ KM(ks + 1)));
      acc2a = mfma32(a0, b2f[ks], acc2a);
      acc2b = mfma32(a1, b2f[ks + 1], acc2b);
    }
#pragma unroll
    for (int r = 0; r < 16; ++r) {
      const int rl = (r & 3) + ((r >> 2) << 3) + (lh << 2);
      float v = fmaxf(acc2a[r] + acc2b[r] + bv2, 0.f);
      *(unsigned short*)(H2 + (mt2 << 13) + ((cb2 + (rl << 4)) ^ m2)) = f2bf(v);
    }
    // hoist ALL GEMM3 B-fragments + bias across the barrier
    const unsigned short* const bp3g = bp3 + ((size_t)g << 14);
    s8v b3f[8];
#pragma unroll
    for (int ks = 0; ks < 8; ++ks) b3f[ks] = *(const s8v*)(bp3g + (ks << 9));
    const float bv3 = b3[(g << 7) + gc2];
    __syncthreads();

    // ---------- GEMM3: h3 = h2 @ W3[g] + b3[g]; racc += w*h3 ----------
    f16v acc3a = zf16(), acc3b = zf16();
#pragma unroll
    for (int ks = 0; ks < 8; ks += 2) {
      s8v a0 = *(const s8v*)(H2 + (mt2 << 13) + (((ks << 10) + lb) ^ KM(ks)));
      s8v a1 = *(const s8v*)(H2 + (mt2 << 13) + ((((ks + 1) << 10) + lb) ^ KM(ks + 1)));
      acc3a = mfma32(a0, b3f[ks], acc3a);
      acc3b = mfma32(a1, b3f[ks + 1], acc3b);
    }
#pragma unroll
    for (int r = 0; r < 16; ++r) {
      const int rl = (r & 3) + ((r >> 2) << 3) + (lh << 2);
      const int grow = (mt2 << 5) + rl;
      racc[r] += WL[grow * 20 + g] * (acc3a[r] + acc3b[r] + bv3);
    }
  }

  // prefetch GEMM4 ks=0,1 B for both ntiles (fly across the barriers)
  s8v bq4[2][2];
#pragma unroll
  for (int k = 0; k < 2; ++k) {
    bq4[k][0] = *(const s8v*)(bp4a + (k << 9));
    bq4[k][1] = *(const s8v*)(bp4b + (k << 9));
  }
  __syncthreads();  // all GEMM3 H2 reads done
#pragma unroll
  for (int r = 0; r < 16; ++r) {
    const int rl = (r & 3) + ((r >> 2) << 3) + (lh << 2);
    *(unsigned short*)(H2 + (mt2 << 13) + ((cb2 + (rl << 4)) ^ m2)) = f2bf(racc[r]);
  }
  __syncthreads();

  // ---------- GEMM4: out = relu([X | ref] @ Wagg + bagg)  [64,512] ----------
  f16v acc4[2][2];
  acc4[0][0] = zf16(); acc4[0][1] = zf16();
  acc4[1][0] = zf16(); acc4[1][1] = zf16();
#pragma unroll
  for (int ks = 0; ks < 40; ++ks) {
    s8v bn0, bn1;
    if (ks < 38) {
      bn0 = *(const s8v*)(bp4a + ((ks + 2) << 9));
      bn1 = *(const s8v*)(bp4b + ((ks + 2) << 9));
    }
    s8v a0, a1;
    if (ks < 32) {
      a0 = *(const s8v*)(XT + (ks << 10) + (lane << 4));
      a1 = *(const s8v*)(XT + 32768 + (ks << 10) + (lane << 4));
    } else {
      const int hk = ks - 32;
      a0 = *(const s8v*)(H2 + (((hk << 10) + lb) ^ KM(hk)));
      a1 = *(const s8v*)(H2 + 8192 + (((hk << 10) + lb) ^ KM(hk)));
    }
    acc4[0][0] = mfma32(a0, bq4[ks & 1][0], acc4[0][0]);
    acc4[1][0] = mfma32(a1, bq4[ks & 1][0], acc4[1][0]);
    acc4[0][1] = mfma32(a0, bq4[ks & 1][1], acc4[0][1]);
    acc4[1][1] = mfma32(a1, bq4[ks & 1][1], acc4[1][1]);
    if (ks < 38) { bq4[ks & 1][0] = bn0; bq4[ks & 1][1] = bn1; }
  }
  {
    const float bv4a = bagg[(wid << 5) + l31];
    const float bv4b = bagg[((wid + 8) << 5) + l31];
#pragma unroll
    for (int mt = 0; mt < 2; ++mt)
#pragma unroll
      for (int r = 0; r < 16; ++r) {
        const int rl = (r & 3) + ((r >> 2) << 3) + (lh << 2);
        const size_t rbase = (size_t)(row0 + (mt << 5) + rl) << 9;
        out[rbase + (wid << 5) + l31] = fmaxf(acc4[mt][0][r] + bv4a, 0.f);
        out[rbase + ((wid + 8) << 5) + l31] = fmaxf(acc4[mt][1][r] + bv4b, 0.f);
      }
  }
}

// ---------------- workspace layout (bytes) ----------------
#define OFF_W     0u          // w[B][18] f32        : 1179648
#define OFF_XB    1179648u    // xb[B][512] bf16     : 16777216
#define OFF_W1P   17956864u   // packed W1           : 4718592
#define OFF_W2P   22675456u   // packed W2           : 1179648
#define OFF_W3P   23855104u   // packed W3           : 589824
#define OFF_W4P   24444928u   // packed Wagg         : 655360
#define OFF_WAT   25100288u   // [18][512] f32       : 36864  (end 25137152)

extern "C" void kernel_launch(void* const* d_in, const int* in_sizes, int n_in,
                              void* d_out, int out_size, void* d_ws, size_t ws_size,
                              hipStream_t stream) {
  const float* X    = (const float*)d_in[0];
  const float* GV   = (const float*)d_in[1];
  const float* W1   = (const float*)d_in[2];
  const float* b1   = (const float*)d_in[3];
  const float* W2   = (const float*)d_in[4];
  const float* b2   = (const float*)d_in[5];
  const float* W3   = (const float*)d_in[6];
  const float* b3   = (const float*)d_in[7];
  const float* Wa   = (const float*)d_in[8];
  const float* ba   = (const float*)d_in[9];
  const float* Wagg = (const float*)d_in[10];
  const float* bagg = (const float*)d_in[11];
  float* out = (float*)d_out;
  char* ws = (char*)d_ws;

  float* w_ws           = (float*)(ws + OFF_W);
  unsigned short* xb    = (unsigned short*)(ws + OFF_XB);
  unsigned short* w1p   = (unsigned short*)(ws + OFF_W1P);
  unsigned short* w2p   = (unsigned short*)(ws + OFF_W2P);
  unsigned short* w3p   = (unsigned short*)(ws + OFF_W3P);
  unsigned short* w4p   = (unsigned short*)(ws + OFF_W4P);
  float* wat            = (float*)(ws + OFF_WAT);

  k_pack<<<dim3(64, 18), 256, 0, stream>>>(W1, w1p, 512, 256);
  k_pack<<<dim3(16, 18), 256, 0, stream>>>(W2, w2p, 256, 128);
  k_pack<<<dim3(8, 18), 256, 0, stream>>>(W3, w3p, 128, 128);
  k_pack<<<dim3(160, 1), 256, 0, stream>>>(Wagg, w4p, 640, 512);
  k_wat<<<36, 256, 0, stream>>>(Wa, wat);
  k_attn<<<4096, 256, 0, stream>>>(X, GV, wat, ba, w_ws, xb);
  k_main<<<256, 512, 0, stream>>>(xb, w_ws, w1p, w2p, w3p, w4p,
                                  b1, b2, b3, bagg, out);
}

// Round 10
// 164.917 us; speedup vs baseline: 1.2257x; 1.2257x over previous
//
#include <hip/hip_runtime.h>

#define NB 16384
#define ND 512
#define NH 128
#define NHH 256
#define NG 18

typedef short s8v __attribute__((ext_vector_type(8)));
typedef __bf16 bf8v __attribute__((ext_vector_type(8)));
typedef float f16v __attribute__((ext_vector_type(16)));
typedef unsigned int u4v __attribute__((ext_vector_type(4)));

static __device__ __forceinline__ unsigned short f2bf(float f) {
  unsigned int u = __builtin_bit_cast(unsigned int, f);
  u += 0x7FFFu + ((u >> 16) & 1u);
  return (unsigned short)(u >> 16);
}

static __device__ __forceinline__ unsigned pk2(float a, float b) {
  return (unsigned)f2bf(a) | ((unsigned)f2bf(b) << 16);
}

static __device__ __forceinline__ f16v mfma32(s8v a, s8v b, f16v c) {
  return __builtin_amdgcn_mfma_f32_32x32x16_bf16(
      __builtin_bit_cast(bf8v, a), __builtin_bit_cast(bf8v, b), c, 0, 0, 0);
}

static __device__ __forceinline__ f16v zf16() {
  f16v v;
#pragma unroll
  for (int i = 0; i < 16; ++i) v[i] = 0.f;
  return v;
}

// per-ks compile-time swizzle XOR for fragment-linear H1/H2 reads
#define KM(ks) (((((ks) & 1) << 5)) | ((((ks) >> 1) & 1) << 6))

// pack W [G][K][N] f32 -> B-fragment-linear bf16 for mfma_32x32x16
__global__ __launch_bounds__(256) void k_pack(const float* __restrict__ in,
                                              unsigned short* __restrict__ out,
                                              int K, int N) {
  const int g = blockIdx.y;
  const int c = blockIdx.x * 256 + threadIdx.x;
  const int nk = K >> 4;
  const int l = c & 63;
  const int t = c >> 6;
  const int nt = t / nk;
  const int ks = t - nt * nk;
  const int k0 = (ks << 4) + ((l >> 5) << 3);
  const int col = (nt << 5) + (l & 31);
  const float* ip = in + (size_t)g * K * N + (size_t)k0 * N + col;
  u4v pk;
#pragma unroll
  for (int j = 0; j < 4; ++j)
    pk[j] = pk2(ip[(size_t)(2 * j) * N], ip[(size_t)(2 * j + 1) * N]);
  *(u4v*)(out + (size_t)g * K * N + ((size_t)c << 3)) = pk;
}

// pack Wa [512][18] -> fragment stream [32 ks][64 lane][8], cols >= 18 zeroed
__global__ __launch_bounds__(256) void k_packa(const float* __restrict__ wa,
                                               unsigned short* __restrict__ wap) {
  const int t = blockIdx.x * 256 + threadIdx.x;  // 0..2047
  const int ks = t >> 6, l = t & 63;
  const int col = l & 31;
  const int k0 = (ks << 4) + ((l >> 5) << 3);
  u4v pk;
  if (col < 18) {
    const float* ip = wa + (size_t)k0 * NG + col;
#pragma unroll
    for (int j = 0; j < 4; ++j)
      pk[j] = pk2(ip[(size_t)(2 * j) * NG], ip[(size_t)(2 * j + 1) * NG]);
  } else {
    pk[0] = pk[1] = pk[2] = pk[3] = 0u;
  }
  *(u4v*)(wap + ((size_t)t << 3)) = pk;
}

// fused attn + experts + aggregation. 1 block = 64 rows, 8 waves, mfma 32x32x16.
__global__ __launch_bounds__(512, 1) void k_main(
    const float* __restrict__ X,              // [B][512] f32
    const float* __restrict__ GV,             // [B][18]
    const unsigned short* __restrict__ w1p,   // packed [18][512x256]
    const unsigned short* __restrict__ w2p,   // packed [18][256x128]
    const unsigned short* __restrict__ w3p,   // packed [18][128x128]
    const unsigned short* __restrict__ w4p,   // packed [640x512]
    const unsigned short* __restrict__ wap,   // packed Wa [512x32]
    const float* __restrict__ b1, const float* __restrict__ b2,
    const float* __restrict__ b3, const float* __restrict__ bagg,
    const float* __restrict__ ba,
    float* __restrict__ out) {
  __shared__ __align__(16) char smem[119808];
  char* const XT = smem;                      // [2][32][1024] = 64KB (linear)
  char* const H1 = smem + 65536;              // [2][16][1024] = 32KB (swz); prologue: Lsm
  char* const H2 = smem + 98304;              // [2][8][1024]  = 16KB (swz)
  float* const WL = (float*)(smem + 114688);  // [64][20]

  const int tid = threadIdx.x;
  const int row0 = blockIdx.x << 6;
  const int wid = tid >> 6, lane = tid & 63;
  const int l31 = lane & 31, lh = lane >> 5;
  const int lb = (lane << 4) ^ (lh << 4);     // swizzled read lane-base

  // ---- stage XT (f32 -> bf16) in fragment-linear order
#pragma unroll
  for (int i = 0; i < 8; ++i) {
    int ck = (i << 9) + tid;                  // chunk 0..4095
    int mt = ck >> 11, ks = (ck >> 6) & 31, l = ck & 63;
    int grow = row0 + (mt << 5) + (l & 31);
    int c8 = (ks << 1) + (l >> 5);
    const float* xp = X + ((size_t)grow << 9) + (c8 << 3);
    float4 xa = *(const float4*)xp;
    float4 xc = *(const float4*)(xp + 4);
    u4v p;
    p[0] = pk2(xa.x, xa.y); p[1] = pk2(xa.z, xa.w);
    p[2] = pk2(xc.x, xc.y); p[3] = pk2(xc.z, xc.w);
    *(u4v*)(XT + (ck << 4)) = p;
  }

  // GEMM1 per-wave B base (col-tile = wid) and depth-8 queue prefetch (g=0)
  const unsigned short* const bp1 = w1p + (wid << 14) + (lane << 3);
  s8v bq[8];
#pragma unroll
  for (int i = 0; i < 8; ++i) bq[i] = *(const s8v*)(bp1 + (i << 9));

  __syncthreads();

  // ---- attention logits: L = X @ Wa + ba via MFMA (waves 0,1)
  float* const Lsm = (float*)H1;              // [64][33] f32
  if (wid < 2) {
    f16v accL = zf16();
    const unsigned short* const bpa = wap + (lane << 3);
#pragma unroll
    for (int ks = 0; ks < 32; ++ks) {
      s8v a = *(const s8v*)(XT + (wid << 15) + (ks << 10) + (lane << 4));
      s8v b = *(const s8v*)(bpa + (ks << 9));
      accL = mfma32(a, b, accL);
    }
    const float bav = (l31 < NG) ? ba[l31] : 0.f;
#pragma unroll
    for (int r = 0; r < 16; ++r) {
      const int rl = (r & 3) + ((r >> 2) << 3) + (lh << 2);
      Lsm[((wid << 5) + rl) * 33 + l31] = accL[r] + bav;
    }
  }
  __syncthreads();

  // ---- softmax * genre mask -> WL  (8 lanes per wave, one row each)
  if (lane < 8) {
    const int row = (wid << 3) + lane;
    float lg[NG], mx = -3.4e38f;
#pragma unroll
    for (int g = 0; g < NG; ++g) { lg[g] = Lsm[row * 33 + g]; mx = fmaxf(mx, lg[g]); }
    float s = 0.f;
#pragma unroll
    for (int g = 0; g < NG; ++g) { lg[g] = expf(lg[g] - mx); s += lg[g]; }
    const float inv = 1.f / s;
#pragma unroll
    for (int g = 0; g < NG; ++g) {
      float gv = GV[(size_t)(row0 + row) * NG + g];
      WL[row * 20 + g] = gv > 0.f ? lg[g] * inv * gv : 0.f;
    }
  }

  // ---- wave tile assignment
  const int nt2 = wid & 3, mt2 = wid >> 2;    // GEMM2/3 tile
  const unsigned short* const bp2 = w2p + (nt2 << 13) + (lane << 3);
  const unsigned short* const bp3 = w3p + (nt2 << 12) + (lane << 3);
  const unsigned short* const bp4a = w4p + (size_t)wid * 20480 + (lane << 3);
  const unsigned short* const bp4b = w4p + (size_t)(wid + 8) * 20480 + (lane << 3);

  // per-lane swizzled write bases (genre-invariant)
  const int gc1 = (wid << 5) + l31;           // GEMM1 col
  const int gc2 = (nt2 << 5) + l31;           // GEMM2/3 col
  const int cb1 = ((gc1 >> 4) << 10) + (((gc1 >> 3) & 1) << 9) + ((gc1 & 7) << 1);
  const int cb2 = ((gc2 >> 4) << 10) + (((gc2 >> 3) & 1) << 9) + ((gc2 & 7) << 1);
  const int m1 = (((cb1 >> 9) & 1) << 4) | (((cb1 >> 10) & 1) << 5) | (((cb1 >> 11) & 1) << 6);
  const int m2 = (((cb2 >> 9) & 1) << 4) | (((cb2 >> 10) & 1) << 5) | (((cb2 >> 11) & 1) << 6);

  f16v racc = zf16();
  __syncthreads();

  for (int g = 0; g < NG; ++g) {
    const unsigned short* const bp1g = bp1 + (size_t)g * 131072;
    // ---------- GEMM1: h1 = relu(X @ W1[g] + b1[g])  [64,256] ----------
    // 2 row-tiles x 1 col-tile per wave; 4 acc chains; depth-8 B queue.
    f16v accA0 = zf16(), accA1 = zf16(), accB0 = zf16(), accB1 = zf16();
#pragma unroll
    for (int ks = 0; ks < 32; ++ks) {
      s8v bn;
      const bool havenext = (ks < 24) || (g + 1 < NG);
      if (havenext) {
        size_t off = (ks < 24) ? (size_t)((ks + 8) << 9)
                               : (size_t)131072 + ((ks - 24) << 9);
        bn = *(const s8v*)(bp1g + off);
      }
      s8v a0 = *(const s8v*)(XT + (ks << 10) + (lane << 4));
      s8v a1 = *(const s8v*)(XT + 32768 + (ks << 10) + (lane << 4));
      if (ks & 1) {
        accA1 = mfma32(a0, bq[ks & 7], accA1);
        accB1 = mfma32(a1, bq[ks & 7], accB1);
      } else {
        accA0 = mfma32(a0, bq[ks & 7], accA0);
        accB0 = mfma32(a1, bq[ks & 7], accB0);
      }
      if (havenext) bq[ks & 7] = bn;
    }
    {
      const float bv1 = b1[(g << 8) + gc1];
#pragma unroll
      for (int r = 0; r < 16; ++r) {
        const int rl = (r & 3) + ((r >> 2) << 3) + (lh << 2);
        float vA = fmaxf(accA0[r] + accA1[r] + bv1, 0.f);
        float vB = fmaxf(accB0[r] + accB1[r] + bv1, 0.f);
        const int boff = (cb1 + (rl << 4)) ^ m1;
        *(unsigned short*)(H1 + boff) = f2bf(vA);
        *(unsigned short*)(H1 + 16384 + boff) = f2bf(vB);
      }
    }
    // hoist ALL GEMM2 B-fragments + bias across the barrier
    const unsigned short* const bp2g = bp2 + ((size_t)g << 15);
    s8v b2f[16];
#pragma unroll
    for (int ks = 0; ks < 16; ++ks) b2f[ks] = *(const s8v*)(bp2g + (ks << 9));
    const float bv2 = b2[(g << 7) + gc2];
    __syncthreads();

    // ---------- GEMM2: h2 = relu(h1 @ W2[g] + b2[g])  [64,128] ----------
    f16v acc2a = zf16(), acc2b = zf16();
#pragma unroll
    for (int ks = 0; ks < 16; ks += 2) {
      s8v a0 = *(const s8v*)(H1 + (mt2 << 14) + (((ks << 10) + lb) ^ KM(ks)));
      s8v a1 = *(const s8v*)(H1 + (mt2 << 14) + ((((ks + 1) << 10) + lb) ^ KM(ks + 1)));
      acc2a = mfma32(a0, b2f[ks], acc2a);
      acc2b = mfma32(a1, b2f[ks + 1], acc2b);
    }
#pragma unroll
    for (int r = 0; r < 16; ++r) {
      const int rl = (r & 3) + ((r >> 2) << 3) + (lh << 2);
      float v = fmaxf(acc2a[r] + acc2b[r] + bv2, 0.f);
      *(unsigned short*)(H2 + (mt2 << 13) + ((cb2 + (rl << 4)) ^ m2)) = f2bf(v);
    }
    // hoist ALL GEMM3 B-fragments + bias across the barrier
    const unsigned short* const bp3g = bp3 + ((size_t)g << 14);
    s8v b3f[8];
#pragma unroll
    for (int ks = 0; ks < 8; ++ks) b3f[ks] = *(const s8v*)(bp3g + (ks << 9));
    const float bv3 = b3[(g << 7) + gc2];
    __syncthreads();

    // ---------- GEMM3: h3 = h2 @ W3[g] + b3[g]; racc += w*h3 ----------
    f16v acc3a = zf16(), acc3b = zf16();
#pragma unroll
    for (int ks = 0; ks < 8; ks += 2) {
      s8v a0 = *(const s8v*)(H2 + (mt2 << 13) + (((ks << 10) + lb) ^ KM(ks)));
      s8v a1 = *(const s8v*)(H2 + (mt2 << 13) + ((((ks + 1) << 10) + lb) ^ KM(ks + 1)));
      acc3a = mfma32(a0, b3f[ks], acc3a);
      acc3b = mfma32(a1, b3f[ks + 1], acc3b);
    }
#pragma unroll
    for (int r = 0; r < 16; ++r) {
      const int rl = (r & 3) + ((r >> 2) << 3) + (lh << 2);
      const int grow = (mt2 << 5) + rl;
      racc[r] += WL[grow * 20 + g] * (acc3a[r] + acc3b[r] + bv3);
    }
  }

  // prefetch GEMM4 depth-4 queue for both col-tiles (flies across the barriers)
  s8v bq4[4][2];
#pragma unroll
  for (int k = 0; k < 4; ++k) {
    bq4[k][0] = *(const s8v*)(bp4a + (k << 9));
    bq4[k][1] = *(const s8v*)(bp4b + (k << 9));
  }
  __syncthreads();  // all GEMM3 H2 reads done
#pragma unroll
  for (int r = 0; r < 16; ++r) {
    const int rl = (r & 3) + ((r >> 2) << 3) + (lh << 2);
    *(unsigned short*)(H2 + (mt2 << 13) + ((cb2 + (rl << 4)) ^ m2)) = f2bf(racc[r]);
  }
  __syncthreads();

  // ---------- GEMM4: out = relu([X | ref] @ Wagg + bagg)  [64,512] ----------
  f16v acc4[2][2];
  acc4[0][0] = zf16(); acc4[0][1] = zf16();
  acc4[1][0] = zf16(); acc4[1][1] = zf16();
#pragma unroll
  for (int ks = 0; ks < 40; ++ks) {
    s8v bn0, bn1;
    if (ks < 36) {
      bn0 = *(const s8v*)(bp4a + ((ks + 4) << 9));
      bn1 = *(const s8v*)(bp4b + ((ks + 4) << 9));
    }
    s8v a0, a1;
    if (ks < 32) {
      a0 = *(const s8v*)(XT + (ks << 10) + (lane << 4));
      a1 = *(const s8v*)(XT + 32768 + (ks << 10) + (lane << 4));
    } else {
      const int hk = ks - 32;
      a0 = *(const s8v*)(H2 + (((hk << 10) + lb) ^ KM(hk)));
      a1 = *(const s8v*)(H2 + 8192 + (((hk << 10) + lb) ^ KM(hk)));
    }
    acc4[0][0] = mfma32(a0, bq4[ks & 3][0], acc4[0][0]);
    acc4[1][0] = mfma32(a1, bq4[ks & 3][0], acc4[1][0]);
    acc4[0][1] = mfma32(a0, bq4[ks & 3][1], acc4[0][1]);
    acc4[1][1] = mfma32(a1, bq4[ks & 3][1], acc4[1][1]);
    if (ks < 36) { bq4[ks & 3][0] = bn0; bq4[ks & 3][1] = bn1; }
  }
  {
    const float bv4a = bagg[(wid << 5) + l31];
    const float bv4b = bagg[((wid + 8) << 5) + l31];
#pragma unroll
    for (int mt = 0; mt < 2; ++mt)
#pragma unroll
      for (int r = 0; r < 16; ++r) {
        const int rl = (r & 3) + ((r >> 2) << 3) + (lh << 2);
        const size_t rbase = (size_t)(row0 + (mt << 5) + rl) << 9;
        out[rbase + (wid << 5) + l31] = fmaxf(acc4[mt][0][r] + bv4a, 0.f);
        out[rbase + ((wid + 8) << 5) + l31] = fmaxf(acc4[mt][1][r] + bv4b, 0.f);
      }
  }
}

// ---------------- workspace layout (bytes) ----------------
#define OFF_W1P   0u          // packed W1   : 4718592
#define OFF_W2P   4718592u    // packed W2   : 1179648
#define OFF_W3P   5898240u    // packed W3   : 589824
#define OFF_W4P   6488064u    // packed Wagg : 655360
#define OFF_WAP   7143424u    // packed Wa   : 32768   (end 7176192)

extern "C" void kernel_launch(void* const* d_in, const int* in_sizes, int n_in,
                              void* d_out, int out_size, void* d_ws, size_t ws_size,
                              hipStream_t stream) {
  const float* X    = (const float*)d_in[0];
  const float* GV   = (const float*)d_in[1];
  const float* W1   = (const float*)d_in[2];
  const float* b1   = (const float*)d_in[3];
  const float* W2   = (const float*)d_in[4];
  const float* b2   = (const float*)d_in[5];
  const float* W3   = (const float*)d_in[6];
  const float* b3   = (const float*)d_in[7];
  const float* Wa   = (const float*)d_in[8];
  const float* ba   = (const float*)d_in[9];
  const float* Wagg = (const float*)d_in[10];
  const float* bagg = (const float*)d_in[11];
  float* out = (float*)d_out;
  char* ws = (char*)d_ws;

  unsigned short* w1p = (unsigned short*)(ws + OFF_W1P);
  unsigned short* w2p = (unsigned short*)(ws + OFF_W2P);
  unsigned short* w3p = (unsigned short*)(ws + OFF_W3P);
  unsigned short* w4p = (unsigned short*)(ws + OFF_W4P);
  unsigned short* wap = (unsigned short*)(ws + OFF_WAP);

  k_pack<<<dim3(64, 18), 256, 0, stream>>>(W1, w1p, 512, 256);
  k_pack<<<dim3(16, 18), 256, 0, stream>>>(W2, w2p, 256, 128);
  k_pack<<<dim3(8, 18), 256, 0, stream>>>(W3, w3p, 128, 128);
  k_pack<<<dim3(160, 1), 256, 0, stream>>>(Wagg, w4p, 640, 512);
  k_packa<<<8, 256, 0, stream>>>(Wa, wap);
  k_main<<<256, 512, 0, stream>>>(X, GV, w1p, w2p, w3p, w4p, wap,
                                  b1, b2, b3, bagg, ba, out);
}